// Round 9
// baseline (217.613 us; speedup 1.0000x reference)
//
#include <hip/hip_runtime.h>

typedef unsigned short u16;
typedef unsigned int u32;
typedef unsigned char u8;

typedef int i32x4 __attribute__((ext_vector_type(4)));

#define AS1 __attribute__((address_space(1)))
#define AS3 __attribute__((address_space(3)))

// ---- per-row symmetric i8 quantization of x: one block (256 thr) per row ----
// W is int4 codes in [-8,7]: EXACT in i8 (zero error); only x carries quant error.
__global__ __launch_bounds__(256) void quant_x_kernel(
    const float* __restrict__ x, u8* __restrict__ xq, float* __restrict__ sx, int K)
{
    const int r = blockIdx.x;
    const int t = threadIdx.x;
    const float* xr = x + (size_t)r * K;
    float4 v[4];
    float m = 0.f;
#pragma unroll
    for (int i = 0; i < 4; ++i) {
        v[i] = *(const float4*)(xr + t * 16 + i * 4);
        m = fmaxf(m, fmaxf(fmaxf(fabsf(v[i].x), fabsf(v[i].y)),
                           fmaxf(fabsf(v[i].z), fabsf(v[i].w))));
    }
#pragma unroll
    for (int s = 32; s; s >>= 1) m = fmaxf(m, __shfl_xor(m, s));
    __shared__ float wm[4];
    if ((t & 63) == 0) wm[t >> 6] = m;
    __syncthreads();
    m = fmaxf(fmaxf(wm[0], wm[1]), fmaxf(wm[2], wm[3]));
    const float inv = 127.f / fmaxf(m, 1e-20f);
    if (t == 0) sx[r] = m * (1.f / 127.f);
    u32 o[4];
#pragma unroll
    for (int i = 0; i < 4; ++i) {
        int q0 = (int)rintf(v[i].x * inv), q1 = (int)rintf(v[i].y * inv);
        int q2 = (int)rintf(v[i].z * inv), q3 = (int)rintf(v[i].w * inv);
        o[i] = (u32)(q0 & 255) | ((u32)(q1 & 255) << 8) |
               ((u32)(q2 & 255) << 16) | ((u32)(q3 & 255) << 24);
    }
    *(uint4*)(xq + (size_t)r * K + t * 16) = make_uint4(o[0], o[1], o[2], o[3]);
}

__device__ __forceinline__ u32 pk8(int4 a) {
    return (u32)(a.x & 255) | ((u32)(a.y & 255) << 8) |
           ((u32)(a.z & 255) << 16) | ((u32)(a.w & 255) << 24);
}

// int32 codes [-8,7] -> i8 (exact)
__global__ void quant_w_kernel(const int4* __restrict__ q, uint4* __restrict__ y, int n16) {
    int stride = gridDim.x * blockDim.x;
    for (int i = blockIdx.x * blockDim.x + threadIdx.x; i < n16; i += stride) {
        int4 a = q[4 * i], b = q[4 * i + 1], c = q[4 * i + 2], d = q[4 * i + 3];
        y[i] = make_uint4(pk8(a), pk8(b), pk8(c), pk8(d));
    }
}

// ===== 256x256 i8 GEMM, 4 waves x (128x128 wave tile), 1 barrier / K-tile =====
// out[m][n] = acc[m][n] * sx[m] * scale[n] + bias[n]
// mfma_i32_16x16x64_i8, BKB=128. LDS reads cut to (128+128)x128 x4 waves = 128KB/K-tile
// (was 192KB with 8x 128x64 waves). Regions of {64 MFMA on prev-read regs; 16 read-ahead
// ds_reads; [16 stage issues]}. Sync ledger (2 gates per 2 K-tiles, each lgkm0+vmcnt(0)+bar):
//  R1(tE,KS0): reads [buf0,KS1]                    | GATE A (buf1 = tO ready; buf0 reads done -> R2 may stage buf0)
//  R2(tE,KS1): reads [buf1,KS0]; stage tE+2 -> buf0
//  R3(tO,KS0): reads [buf1,KS1]                    | GATE B (buf0 = tE+2 ready; buf1 reads done -> R4 may stage buf1)
//  R4(tO,KS1): reads [buf0,KS0](next); stage tO+2 -> buf1
// Every gate's drained loads were issued >=1.5 regions (~1200cyc) earlier (> HBM 900cyc).
// Swizzle (verified 0-conflict R7): physical 16B slot p at row r holds logical p^(r&7);
// staging pre-swizzles the global source; readers XOR (l&7) into the slot index.

#define BM 256
#define BN 256
#define BKB 128   // K-bytes per tile (=128 i8)

__global__ __launch_bounds__(256, 1) void gemm256_i8(
    const u8* __restrict__ A,       // [M][K] i8 (x quantized per-row)
    const u8* __restrict__ W,       // [N][K] i8 (exact int4)
    const float* __restrict__ sx,   // [M] x row scales
    const float* __restrict__ scale,
    const float* __restrict__ bias,
    float* __restrict__ C,
    int M, int N, int K)
{
    __shared__ alignas(1024) char lds[131072];  // buf0: A@0 B@32768 ; buf1: A@65536 B@98304

    const int nwg = gridDim.x;
    int bid = blockIdx.x;
    if ((nwg & 7) == 0) { int cpx = nwg >> 3; bid = (bid & 7) * cpx + (bid >> 3); }
    const int ntn = N / BN;
    const int tm = bid / ntn, tn = bid % ntn;

    const int t = threadIdx.x;
    const int l = t & 63;
    const int w = t >> 6;                    // 4 waves: 2wm x 2wn
    const int wm = w >> 1, wn = w & 1;       // wave tile 128x128
    const size_t Kz = (size_t)K;             // row stride in BYTES (i8)

    // ---- staging: linear LDS dest; pre-swizzled global source.
    // chunk = 32 rows x 128 B = 4 KB (one gload_lds across 256 thr; wave w covers rows w*8..w*8+7)
    const int sRow = t >> 3;                              // 0..31 within chunk
    const int sCol = (((t & 7) ^ ((t >> 3) & 7)) * 16);   // logical byte offset in row
    const u8* aSrc = A + (size_t)(tm * BM + sRow) * Kz + sCol;
    const u8* bSrc = W + (size_t)(tn * BN + sRow) * Kz + sCol;
    const int wByte = w * 1024;

    char* dA0 = lds +      0 + wByte;
    char* dB0 = lds + 32768 + wByte;
    char* dA1 = lds + 65536 + wByte;
    char* dB1 = lds + 98304 + wByte;

    // ---- reader bases: logical 16B slot = (l>>4) | (KS<<2); physical = logical ^ (l&7).
    // row & 7 == l & 7 for all fragment rows (bases are multiples of 16 rows).
    const int rowA = (wm * 128 + (l & 15)) * 128;
    const int rowB = (wn * 128 + (l & 15)) * 128;
    const int sl0 = (((l >> 4) | 0) ^ (l & 7)) * 16;   // KS=0: k 0..63
    const int sl1 = (((l >> 4) | 4) ^ (l & 7)) * 16;   // KS=1: k 64..127

    const char* aBase0 = lds +      0 + rowA;
    const char* bBase0 = lds + 32768 + rowB;
    const char* aBase1 = lds + 65536 + rowA;
    const char* bBase1 = lds + 98304 + rowB;

    i32x4 acc[8][8];
#pragma unroll
    for (int i = 0; i < 8; ++i)
#pragma unroll
        for (int j = 0; j < 8; ++j) acc[i][j] = (i32x4){0, 0, 0, 0};

    const int NT = K / BKB;   // 32 K-tiles

    auto stageTile = [&](char* dstA, char* dstB, int kt) {
#pragma unroll
        for (int c = 0; c < 8; ++c)
            __builtin_amdgcn_global_load_lds(
                (const AS1 void*)(aSrc + (size_t)c * 32 * Kz + (size_t)kt * BKB),
                (AS3 void*)(dstA + c * 4096), 16, 0, 0);
#pragma unroll
        for (int c = 0; c < 8; ++c)
            __builtin_amdgcn_global_load_lds(
                (const AS1 void*)(bSrc + (size_t)c * 32 * Kz + (size_t)kt * BKB),
                (AS3 void*)(dstB + c * 4096), 16, 0, 0);
    };
    auto readF = [&](i32x4 (&dst)[8], const char* base, int sl) {
#pragma unroll
        for (int f = 0; f < 8; ++f)
            dst[f] = *(const i32x4*)(base + f * 2048 + sl);
    };
    auto mfma64 = [&](i32x4 (&bf)[8], i32x4 (&af)[8]) {
#pragma unroll
        for (int f = 0; f < 8; ++f)
#pragma unroll
            for (int fn = 0; fn < 8; ++fn)
                acc[f][fn] = __builtin_amdgcn_mfma_i32_16x16x64_i8(
                    bf[fn], af[f], acc[f][fn], 0, 0, 0);  // swapped: D col->m (R7-verified)
    };

#define SYNC_GATE  do { \
    asm volatile("s_waitcnt lgkmcnt(0)" ::: "memory"); \
    asm volatile("s_waitcnt vmcnt(0)"  ::: "memory"); \
    __builtin_amdgcn_s_barrier(); } while (0)

    // ---- prologue: tile0 -> buf0, tile1 -> buf1; drain tile0 (keep tile1 in flight)
    stageTile(dA0, dB0, 0);
    stageTile(dA1, dB1, 1);
    asm volatile("s_waitcnt vmcnt(16)" ::: "memory");
    __builtin_amdgcn_s_barrier();

    i32x4 afrP[8], bfrP[8], afrQ[8], bfrQ[8];
    readF(afrP, aBase0, sl0);    // primer: [t0, KS0]
    readF(bfrP, bBase0, sl0);

#pragma unroll 1
    for (int i = 0; i < NT / 2; ++i) {
        const int tE2 = (2 * i + 2) & (NT - 1);   // wraps harmlessly on last iter
        const int tO2 = (2 * i + 3) & (NT - 1);
        // R1: MFMA tE/KS0; read [buf0, KS1]
        mfma64(bfrP, afrP);
        readF(afrQ, aBase0, sl1);
        readF(bfrQ, bBase0, sl1);
        SYNC_GATE;   // gate A: buf1(tO) ready; buf0 reads drained -> R2 may stage buf0
        // R2: MFMA tE/KS1; read [buf1, KS0]; stage tE+2 -> buf0
        mfma64(bfrQ, afrQ);
        readF(afrP, aBase1, sl0);
        readF(bfrP, bBase1, sl0);
        stageTile(dA0, dB0, tE2);
        // R3: MFMA tO/KS0; read [buf1, KS1]
        mfma64(bfrP, afrP);
        readF(afrQ, aBase1, sl1);
        readF(bfrQ, bBase1, sl1);
        SYNC_GATE;   // gate B: buf0(tE+2) ready; buf1 reads drained -> R4 may stage buf1
        // R4: MFMA tO/KS1; read [buf0, KS0] (next super); stage tO+2 -> buf1
        mfma64(bfrQ, afrQ);
        readF(afrP, aBase0, sl0);
        readF(bfrP, bBase0, sl0);
        stageTile(dA1, dB1, tO2);
    }

    // ---- epilogue (swapped D, R7-verified): col(l&15)->m, row((l>>4)*4+r)->n
    const int mB = tm * BM + wm * 128 + (l & 15);
    const int nB = tn * BN + wn * 128 + 4 * (l >> 4);
    float sxv[8];
#pragma unroll
    for (int f = 0; f < 8; ++f) sxv[f] = sx[mB + f * 16];
#pragma unroll
    for (int fn = 0; fn < 8; ++fn) {
        const int n0 = nB + fn * 16;
        const float4 s4 = *(const float4*)(scale + n0);
        const float4 b4 = *(const float4*)(bias + n0);
#pragma unroll
        for (int f = 0; f < 8; ++f) {
            const int m = mB + f * 16;
            const float sm = sxv[f];
            float4 v;
            v.x = (float)acc[f][fn][0] * (sm * s4.x) + b4.x;
            v.y = (float)acc[f][fn][1] * (sm * s4.y) + b4.y;
            v.z = (float)acc[f][fn][2] * (sm * s4.z) + b4.z;
            v.w = (float)acc[f][fn][3] * (sm * s4.w) + b4.w;
            *(float4*)(C + (size_t)m * N + n0) = v;
        }
    }
#undef SYNC_GATE
}

extern "C" void kernel_launch(void* const* d_in, const int* in_sizes, int n_in,
                              void* d_out, int out_size, void* d_ws, size_t ws_size,
                              hipStream_t stream) {
    const float* x     = (const float*)d_in[0];
    const int*   qw    = (const int*)d_in[1];
    const float* scale = (const float*)d_in[2];
    const float* bias  = (const float*)d_in[3];
    float*       out   = (float*)d_out;

    const int N = in_sizes[2];            // DOUT = 4096
    const int K = in_sizes[1] / N;        // DIN  = 4096
    const int M = in_sizes[0] / K;        // B*S  = 8192

    // workspace: xq [M*K] i8, wq [N*K] i8, sx [M] f32  (~50.4 MB)
    u8*    xq = (u8*)d_ws;
    u8*    wq = xq + (size_t)M * K;
    float* sx = (float*)(wq + (size_t)N * K);

    quant_x_kernel<<<M, 256, 0, stream>>>(x, xq, sx, K);
    quant_w_kernel<<<2048, 256, 0, stream>>>((const int4*)qw, (uint4*)wq, (N * K) / 16);

    const int grid = (M / BM) * (N / BN); // 512
    gemm256_i8<<<grid, 256, 0, stream>>>(xq, wq, sx, scale, bias, out, M, N, K);
}

// Round 10
// 200.347 us; speedup vs baseline: 1.0862x; 1.0862x over previous
//
#include <hip/hip_runtime.h>

typedef unsigned short u16;
typedef unsigned int u32;
typedef unsigned char u8;

typedef int i32x4 __attribute__((ext_vector_type(4)));

#define AS1 __attribute__((address_space(1)))
#define AS3 __attribute__((address_space(3)))

// ---- per-row symmetric i8 quantization of x: one block (256 thr) per row ----
// W is int4 codes in [-8,7]: EXACT in i8 (zero error); only x carries quant error.
__global__ __launch_bounds__(256) void quant_x_kernel(
    const float* __restrict__ x, u8* __restrict__ xq, float* __restrict__ sx, int K)
{
    const int r = blockIdx.x;
    const int t = threadIdx.x;
    const float* xr = x + (size_t)r * K;
    float4 v[4];
    float m = 0.f;
#pragma unroll
    for (int i = 0; i < 4; ++i) {
        v[i] = *(const float4*)(xr + t * 16 + i * 4);
        m = fmaxf(m, fmaxf(fmaxf(fabsf(v[i].x), fabsf(v[i].y)),
                           fmaxf(fabsf(v[i].z), fabsf(v[i].w))));
    }
#pragma unroll
    for (int s = 32; s; s >>= 1) m = fmaxf(m, __shfl_xor(m, s));
    __shared__ float wm[4];
    if ((t & 63) == 0) wm[t >> 6] = m;
    __syncthreads();
    m = fmaxf(fmaxf(wm[0], wm[1]), fmaxf(wm[2], wm[3]));
    const float inv = 127.f / fmaxf(m, 1e-20f);
    if (t == 0) sx[r] = m * (1.f / 127.f);
    u32 o[4];
#pragma unroll
    for (int i = 0; i < 4; ++i) {
        int q0 = (int)rintf(v[i].x * inv), q1 = (int)rintf(v[i].y * inv);
        int q2 = (int)rintf(v[i].z * inv), q3 = (int)rintf(v[i].w * inv);
        o[i] = (u32)(q0 & 255) | ((u32)(q1 & 255) << 8) |
               ((u32)(q2 & 255) << 16) | ((u32)(q3 & 255) << 24);
    }
    *(uint4*)(xq + (size_t)r * K + t * 16) = make_uint4(o[0], o[1], o[2], o[3]);
}

__device__ __forceinline__ u32 pk8(int4 a) {
    return (u32)(a.x & 255) | ((u32)(a.y & 255) << 8) |
           ((u32)(a.z & 255) << 16) | ((u32)(a.w & 255) << 24);
}

// int32 codes [-8,7] -> i8 (exact)
__global__ void quant_w_kernel(const int4* __restrict__ q, uint4* __restrict__ y, int n16) {
    int stride = gridDim.x * blockDim.x;
    for (int i = blockIdx.x * blockDim.x + threadIdx.x; i < n16; i += stride) {
        int4 a = q[4 * i], b = q[4 * i + 1], c = q[4 * i + 2], d = q[4 * i + 3];
        y[i] = make_uint4(pk8(a), pk8(b), pk8(c), pk8(d));
    }
}

// ===== 128x128 i8 GEMM, 4 waves (64x64 each), 64KB LDS => 2 blocks/CU =====
// out[m][n] = acc[m][n] * sx[m] * scale[n] + bias[n]
// Overlap mechanism: two INDEPENDENT blocks per CU — block A's MFMA region runs
// while block B is in its LDS/stage region (no shared barrier). Within a block:
// one barrier per K-tile: {stage next tile -> buf^1 (8 gload_lds, async);
// read 16 ds_read_b128 from buf; 32 MFMA; vmcnt(0)+lgkm(0); barrier}.
// WAR: stage at phase p writes the buffer whose reads finished at phase p-1
// (lgkm0+barrier between). RAW: vmcnt(0) at end of p covers reads at p+1.
// Swizzle (R7-verified 0-conflict): physical 16B slot s at row r holds logical
// s^(r&7); staging pre-swizzles the global source; readers XOR (l&7).

#define BM 128
#define BN 128
#define BKB 128   // K-bytes per tile (=128 i8)

__global__ __launch_bounds__(256, 2) void gemm128_i8(
    const u8* __restrict__ A,       // [M][K] i8 (x quantized per-row)
    const u8* __restrict__ W,       // [N][K] i8 (exact int4)
    const float* __restrict__ sx,   // [M] x row scales
    const float* __restrict__ scale,
    const float* __restrict__ bias,
    float* __restrict__ C,
    int M, int N, int K)
{
    __shared__ alignas(1024) char lds[65536];  // buf b: A @ b*32768, B @ b*32768+16384

    const int nwg = gridDim.x;
    int bid = blockIdx.x;
    if ((nwg & 7) == 0) { int cpx = nwg >> 3; bid = (bid & 7) * cpx + (bid >> 3); }
    const int ntn = N / BN;
    const int tm = bid / ntn, tn = bid % ntn;

    const int t = threadIdx.x;
    const int l = t & 63;
    const int w = t >> 6;                    // 4 waves: 2wm x 2wn
    const int wm = w >> 1, wn = w & 1;       // wave tile 64x64
    const size_t Kz = (size_t)K;             // row stride in BYTES (i8)

    // ---- staging: linear LDS dest; pre-swizzled global source.
    // chunk = 32 rows x 128 B = 4 KB per gload_lds across 256 thr (wave w: rows w*8..w*8+7)
    const int sRow = t >> 3;                              // 0..31 within chunk
    const int sCol = (((t & 7) ^ ((t >> 3) & 7)) * 16);   // logical byte offset in row
    const u8* aSrc = A + (size_t)(tm * BM + sRow) * Kz + sCol;
    const u8* bSrc = W + (size_t)(tn * BN + sRow) * Kz + sCol;
    const int wByte = w * 1024;

    // ---- reader bases: logical 16B slot = (l>>4)|(KS<<2); physical = logical^(l&7).
    const int rowA = (wm * 64 + (l & 15)) * 128;
    const int rowB = (wn * 64 + (l & 15)) * 128;
    const int sl0 = (((l >> 4) | 0) ^ (l & 7)) * 16;   // KS=0: k 0..63
    const int sl1 = (((l >> 4) | 4) ^ (l & 7)) * 16;   // KS=1: k 64..127

    i32x4 acc[4][4];
#pragma unroll
    for (int i = 0; i < 4; ++i)
#pragma unroll
        for (int j = 0; j < 4; ++j) acc[i][j] = (i32x4){0, 0, 0, 0};

    const int NT = K / BKB;   // 32 K-tiles

    auto stageTile = [&](int b, int kt) {
        char* dA = lds + b * 32768 + wByte;
        char* dB = lds + b * 32768 + 16384 + wByte;
#pragma unroll
        for (int c = 0; c < 4; ++c)
            __builtin_amdgcn_global_load_lds(
                (const AS1 void*)(aSrc + (size_t)c * 32 * Kz + (size_t)kt * BKB),
                (AS3 void*)(dA + c * 4096), 16, 0, 0);
#pragma unroll
        for (int c = 0; c < 4; ++c)
            __builtin_amdgcn_global_load_lds(
                (const AS1 void*)(bSrc + (size_t)c * 32 * Kz + (size_t)kt * BKB),
                (AS3 void*)(dB + c * 4096), 16, 0, 0);
    };

    // ---- prologue
    stageTile(0, 0);
    asm volatile("s_waitcnt vmcnt(0)" ::: "memory");
    __builtin_amdgcn_s_barrier();

#pragma unroll 1
    for (int p = 0; p < NT; ++p) {
        const int cur = p & 1;
        stageTile(cur ^ 1, (p + 1) & (NT - 1));   // async; wraps harmlessly on last iter

        const char* aB = lds + cur * 32768 + rowA;
        const char* bB = lds + cur * 32768 + 16384 + rowB;
        i32x4 aF[2][4], bF[2][4];
#pragma unroll
        for (int f = 0; f < 4; ++f) aF[0][f] = *(const i32x4*)(aB + f * 2048 + sl0);
#pragma unroll
        for (int f = 0; f < 4; ++f) bF[0][f] = *(const i32x4*)(bB + f * 2048 + sl0);
#pragma unroll
        for (int f = 0; f < 4; ++f) aF[1][f] = *(const i32x4*)(aB + f * 2048 + sl1);
#pragma unroll
        for (int f = 0; f < 4; ++f) bF[1][f] = *(const i32x4*)(bB + f * 2048 + sl1);

        __builtin_amdgcn_s_setprio(1);
#pragma unroll
        for (int ks = 0; ks < 2; ++ks)
#pragma unroll
            for (int f = 0; f < 4; ++f)
#pragma unroll
                for (int fn = 0; fn < 4; ++fn)
                    acc[f][fn] = __builtin_amdgcn_mfma_i32_16x16x64_i8(
                        bF[ks][fn], aF[ks][f], acc[f][fn], 0, 0, 0);  // swapped: D col->m
        __builtin_amdgcn_s_setprio(0);

        asm volatile("s_waitcnt vmcnt(0) lgkmcnt(0)" ::: "memory");
        __builtin_amdgcn_s_barrier();
    }

    // ---- epilogue (swapped D, R7-verified): col(l&15)->m, row((l>>4)*4+r)->n
    const int mB = tm * BM + wm * 64 + (l & 15);
    const int nB = tn * BN + wn * 64 + 4 * (l >> 4);
    float sxv[4];
#pragma unroll
    for (int f = 0; f < 4; ++f) sxv[f] = sx[mB + f * 16];
#pragma unroll
    for (int fn = 0; fn < 4; ++fn) {
        const int n0 = nB + fn * 16;
        const float4 s4 = *(const float4*)(scale + n0);
        const float4 b4 = *(const float4*)(bias + n0);
#pragma unroll
        for (int f = 0; f < 4; ++f) {
            const int m = mB + f * 16;
            const float sm = sxv[f];
            float4 v;
            v.x = (float)acc[f][fn][0] * (sm * s4.x) + b4.x;
            v.y = (float)acc[f][fn][1] * (sm * s4.y) + b4.y;
            v.z = (float)acc[f][fn][2] * (sm * s4.z) + b4.z;
            v.w = (float)acc[f][fn][3] * (sm * s4.w) + b4.w;
            *(float4*)(C + (size_t)m * N + n0) = v;
        }
    }
}

extern "C" void kernel_launch(void* const* d_in, const int* in_sizes, int n_in,
                              void* d_out, int out_size, void* d_ws, size_t ws_size,
                              hipStream_t stream) {
    const float* x     = (const float*)d_in[0];
    const int*   qw    = (const int*)d_in[1];
    const float* scale = (const float*)d_in[2];
    const float* bias  = (const float*)d_in[3];
    float*       out   = (float*)d_out;

    const int N = in_sizes[2];            // DOUT = 4096
    const int K = in_sizes[1] / N;        // DIN  = 4096
    const int M = in_sizes[0] / K;        // B*S  = 8192

    // workspace: xq [M*K] i8, wq [N*K] i8, sx [M] f32  (~50.4 MB)
    u8*    xq = (u8*)d_ws;
    u8*    wq = xq + (size_t)M * K;
    float* sx = (float*)(wq + (size_t)N * K);

    quant_x_kernel<<<M, 256, 0, stream>>>(x, xq, sx, K);
    quant_w_kernel<<<2048, 256, 0, stream>>>((const int4*)qw, (uint4*)wq, (N * K) / 16);

    const int grid = (M / BM) * (N / BN); // 2048
    gemm128_i8<<<grid, 256, 0, stream>>>(xq, wq, sx, scale, bias, out, M, N, K);
}

// Round 11
// 196.048 us; speedup vs baseline: 1.1100x; 1.0219x over previous
//
#include <hip/hip_runtime.h>

typedef unsigned int u32;
typedef unsigned char u8;

typedef int i32x4 __attribute__((ext_vector_type(4)));

#define AS1 __attribute__((address_space(1)))
#define AS3 __attribute__((address_space(3)))

// ---- merged quant kernel: blocks [0,M) quantize x rows; blocks [M, M+512) pack W ----
// W is int4 codes in [-8,7]: EXACT in i8 (zero error); only x carries quant error.
__device__ __forceinline__ u32 pk8(int4 a) {
    return (u32)(a.x & 255) | ((u32)(a.y & 255) << 8) |
           ((u32)(a.z & 255) << 16) | ((u32)(a.w & 255) << 24);
}

__global__ __launch_bounds__(256) void quant_xw_kernel(
    const float* __restrict__ x, u8* __restrict__ xq, float* __restrict__ sx,
    const int4* __restrict__ qw, uint4* __restrict__ wq,
    int K, int M, int n16)
{
    const int b = blockIdx.x;
    const int t = threadIdx.x;
    if (b < M) {
        // per-row symmetric i8 quant of x (R7-verified)
        const float* xr = x + (size_t)b * K;
        float4 v[4];
        float m = 0.f;
#pragma unroll
        for (int i = 0; i < 4; ++i) {
            v[i] = *(const float4*)(xr + t * 16 + i * 4);
            m = fmaxf(m, fmaxf(fmaxf(fabsf(v[i].x), fabsf(v[i].y)),
                               fmaxf(fabsf(v[i].z), fabsf(v[i].w))));
        }
#pragma unroll
        for (int s = 32; s; s >>= 1) m = fmaxf(m, __shfl_xor(m, s));
        __shared__ float wm[4];
        if ((t & 63) == 0) wm[t >> 6] = m;
        __syncthreads();
        m = fmaxf(fmaxf(wm[0], wm[1]), fmaxf(wm[2], wm[3]));
        const float inv = 127.f / fmaxf(m, 1e-20f);
        if (t == 0) sx[b] = m * (1.f / 127.f);
        u32 o[4];
#pragma unroll
        for (int i = 0; i < 4; ++i) {
            int q0 = (int)rintf(v[i].x * inv), q1 = (int)rintf(v[i].y * inv);
            int q2 = (int)rintf(v[i].z * inv), q3 = (int)rintf(v[i].w * inv);
            o[i] = (u32)(q0 & 255) | ((u32)(q1 & 255) << 8) |
                   ((u32)(q2 & 255) << 16) | ((u32)(q3 & 255) << 24);
        }
        *(uint4*)(xq + (size_t)b * K + t * 16) = make_uint4(o[0], o[1], o[2], o[3]);
    } else {
        // W int32 codes -> i8 (exact), grid-stride over n16 uint4 outputs
        const int nb = gridDim.x - M;
        const int stride = nb * 256;
        for (int i = (b - M) * 256 + t; i < n16; i += stride) {
            int4 a = qw[4 * i], c = qw[4 * i + 1], d = qw[4 * i + 2], e = qw[4 * i + 3];
            wq[i] = make_uint4(pk8(a), pk8(c), pk8(d), pk8(e));
        }
    }
}

// ===== 256x256 i8 GEMM, 4 waves x (128x128 wave tile), AGPR accumulators =====
// out[m][n] = acc[m][n] * sx[m] * scale[n] + bias[n]
// mfma_i32_16x16x64_i8 via inline asm with "+a" acc (256 AGPRs) so the 2x2/128x128
// geometry (LDS reads 128 KB/K-tile, -33% vs 2x4/128x64) fits without spilling:
// operands ~120 VGPR + 256 AGPR < 512 unified. One barrier per K-tile:
// {stage next tile -> buf^1 (16 async gload_lds); KS0: 16 ds_read_b128 + 64 MFMA;
//  KS1: same; vmcnt(0)+lgkm(0); barrier}. RAW afr/bfr->MFMA is SSA-tracked (compiler
// emits precise lgkmcnt). MFMA->AGPR-read hazards are distance-safe (acc touched
// once/phase; epilogue past final barrier). Swizzle/staging/epilogue: R9-verbatim
// (refcheck'd; R9's failure was spill, not correctness).

#define BM 256
#define BN 256
#define BKB 128   // K-bytes per tile (=128 i8)

__global__ __launch_bounds__(256, 1) void gemm256_i8a(
    const u8* __restrict__ A,       // [M][K] i8 (x quantized per-row)
    const u8* __restrict__ W,       // [N][K] i8 (exact int4)
    const float* __restrict__ sx,   // [M] x row scales
    const float* __restrict__ scale,
    const float* __restrict__ bias,
    float* __restrict__ C,
    int M, int N, int K)
{
    __shared__ alignas(1024) char lds[131072];  // buf b: A @ b*65536, B @ b*65536+32768

    const int nwg = gridDim.x;
    int bid = blockIdx.x;
    if ((nwg & 7) == 0) { int cpx = nwg >> 3; bid = (bid & 7) * cpx + (bid >> 3); }
    const int ntn = N / BN;
    const int tm = bid / ntn, tn = bid % ntn;

    const int t = threadIdx.x;
    const int l = t & 63;
    const int w = t >> 6;                    // 4 waves: 2wm x 2wn
    const int wm = w >> 1, wn = w & 1;       // wave tile 128x128
    const size_t Kz = (size_t)K;             // row stride in BYTES (i8)

    // ---- staging: linear LDS dest; pre-swizzled global source (R9-verbatim).
    // physical 16B slot p at row r holds logical p^(r&7); chunk = 32 rows x 128 B.
    const int sRow = t >> 3;                              // 0..31 within chunk
    const int sCol = (((t & 7) ^ ((t >> 3) & 7)) * 16);   // logical byte offset in row
    const u8* aSrc = A + (size_t)(tm * BM + sRow) * Kz + sCol;
    const u8* bSrc = W + (size_t)(tn * BN + sRow) * Kz + sCol;
    const int wByte = w * 1024;

    // ---- reader bases: logical 16B slot = (l>>4)|(KS<<2); physical = logical^(l&7).
    const int rowA = (wm * 128 + (l & 15)) * 128;
    const int rowB = (wn * 128 + (l & 15)) * 128;
    const int sl0 = (((l >> 4) | 0) ^ (l & 7)) * 16;   // KS=0: k 0..63
    const int sl1 = (((l >> 4) | 4) ^ (l & 7)) * 16;   // KS=1: k 64..127

    i32x4 acc[8][8];
#pragma unroll
    for (int i = 0; i < 8; ++i)
#pragma unroll
        for (int j = 0; j < 8; ++j) acc[i][j] = (i32x4){0, 0, 0, 0};

    const int NT = K / BKB;   // 32 K-tiles

    auto stageTile = [&](int b, int kt) {
        char* dA = lds + b * 65536 + wByte;
        char* dB = lds + b * 65536 + 32768 + wByte;
#pragma unroll
        for (int c = 0; c < 8; ++c)
            __builtin_amdgcn_global_load_lds(
                (const AS1 void*)(aSrc + (size_t)c * 32 * Kz + (size_t)kt * BKB),
                (AS3 void*)(dA + c * 4096), 16, 0, 0);
#pragma unroll
        for (int c = 0; c < 8; ++c)
            __builtin_amdgcn_global_load_lds(
                (const AS1 void*)(bSrc + (size_t)c * 32 * Kz + (size_t)kt * BKB),
                (AS3 void*)(dB + c * 4096), 16, 0, 0);
    };

    // ---- prologue
    stageTile(0, 0);
    asm volatile("s_waitcnt vmcnt(0)" ::: "memory");
    __builtin_amdgcn_s_barrier();

#pragma unroll 1
    for (int p = 0; p < NT; ++p) {
        const int cur = p & 1;
        stageTile(cur ^ 1, (p + 1) & (NT - 1));   // async; wraps harmlessly on last iter

        const char* aB = lds + cur * 65536 + rowA;
        const char* bB = lds + cur * 65536 + 32768 + rowB;

#pragma unroll
        for (int ks = 0; ks < 2; ++ks) {
            const int sl = ks ? sl1 : sl0;
            i32x4 aF[8], bF[8];
#pragma unroll
            for (int f = 0; f < 8; ++f) aF[f] = *(const i32x4*)(aB + f * 2048 + sl);
#pragma unroll
            for (int f = 0; f < 8; ++f) bF[f] = *(const i32x4*)(bB + f * 2048 + sl);
            __builtin_amdgcn_s_setprio(1);
#pragma unroll
            for (int f = 0; f < 8; ++f)
#pragma unroll
                for (int fn = 0; fn < 8; ++fn)
                    // swapped operands (D col->m, R7-verified); acc pinned to AGPRs
                    asm("v_mfma_i32_16x16x64_i8 %0, %1, %2, %0"
                        : "+a"(acc[f][fn])
                        : "v"(bF[fn]), "v"(aF[f]));
            __builtin_amdgcn_s_setprio(0);
        }

        asm volatile("s_waitcnt vmcnt(0) lgkmcnt(0)" ::: "memory");
        __builtin_amdgcn_s_barrier();
    }

    // ---- epilogue (swapped D, R9-verbatim): col(l&15)->m, row((l>>4)*4+r)->n
    const int mB = tm * BM + wm * 128 + (l & 15);
    const int nB = tn * BN + wn * 128 + 4 * (l >> 4);
    float sxv[8];
#pragma unroll
    for (int f = 0; f < 8; ++f) sxv[f] = sx[mB + f * 16];
#pragma unroll
    for (int fn = 0; fn < 8; ++fn) {
        const int n0 = nB + fn * 16;
        const float4 s4 = *(const float4*)(scale + n0);
        const float4 b4 = *(const float4*)(bias + n0);
#pragma unroll
        for (int f = 0; f < 8; ++f) {
            const int m = mB + f * 16;
            const float sm = sxv[f];
            float4 v;
            v.x = (float)acc[f][fn][0] * (sm * s4.x) + b4.x;
            v.y = (float)acc[f][fn][1] * (sm * s4.y) + b4.y;
            v.z = (float)acc[f][fn][2] * (sm * s4.z) + b4.z;
            v.w = (float)acc[f][fn][3] * (sm * s4.w) + b4.w;
            *(float4*)(C + (size_t)m * N + n0) = v;
        }
    }
}

extern "C" void kernel_launch(void* const* d_in, const int* in_sizes, int n_in,
                              void* d_out, int out_size, void* d_ws, size_t ws_size,
                              hipStream_t stream) {
    const float* x     = (const float*)d_in[0];
    const int*   qw    = (const int*)d_in[1];
    const float* scale = (const float*)d_in[2];
    const float* bias  = (const float*)d_in[3];
    float*       out   = (float*)d_out;

    const int N = in_sizes[2];            // DOUT = 4096
    const int K = in_sizes[1] / N;        // DIN  = 4096
    const int M = in_sizes[0] / K;        // B*S  = 8192

    // workspace: xq [M*K] i8, wq [N*K] i8, sx [M] f32  (~50.4 MB)
    u8*    xq = (u8*)d_ws;
    u8*    wq = xq + (size_t)M * K;
    float* sx = (float*)(wq + (size_t)N * K);

    const int n16 = (N * K) / 16;
    quant_xw_kernel<<<M + 512, 256, 0, stream>>>(x, xq, sx, (const int4*)qw,
                                                 (uint4*)wq, K, M, n16);

    const int grid = (M / BM) * (N / BN); // 512
    gemm256_i8a<<<grid, 256, 0, stream>>>(xq, wq, sx, scale, bias, out, M, N, K);
}

// Round 16
// 177.828 us; speedup vs baseline: 1.2237x; 1.1025x over previous
//
#include <hip/hip_runtime.h>

typedef unsigned short u16;
typedef unsigned int u32;
typedef unsigned char u8;

typedef int i32x4 __attribute__((ext_vector_type(4)));
typedef float f32x4 __attribute__((ext_vector_type(4)));

#define AS1 __attribute__((address_space(1)))
#define AS3 __attribute__((address_space(3)))

// ---- per-row symmetric i8 quantization of x: one block (256 thr) per row ----
// W is int4 codes in [-8,7]: EXACT in i8 (zero error); only x carries quant error.
__global__ __launch_bounds__(256) void quant_x_kernel(
    const float* __restrict__ x, u8* __restrict__ xq, float* __restrict__ sx, int K)
{
    const int r = blockIdx.x;
    const int t = threadIdx.x;
    const float* xr = x + (size_t)r * K;
    float4 v[4];
    float m = 0.f;
#pragma unroll
    for (int i = 0; i < 4; ++i) {
        v[i] = *(const float4*)(xr + t * 16 + i * 4);
        m = fmaxf(m, fmaxf(fmaxf(fabsf(v[i].x), fabsf(v[i].y)),
                           fmaxf(fabsf(v[i].z), fabsf(v[i].w))));
    }
#pragma unroll
    for (int s = 32; s; s >>= 1) m = fmaxf(m, __shfl_xor(m, s));
    __shared__ float wm[4];
    if ((t & 63) == 0) wm[t >> 6] = m;
    __syncthreads();
    m = fmaxf(fmaxf(wm[0], wm[1]), fmaxf(wm[2], wm[3]));
    const float inv = 127.f / fmaxf(m, 1e-20f);
    if (t == 0) sx[r] = m * (1.f / 127.f);
    u32 o[4];
#pragma unroll
    for (int i = 0; i < 4; ++i) {
        int q0 = (int)rintf(v[i].x * inv), q1 = (int)rintf(v[i].y * inv);
        int q2 = (int)rintf(v[i].z * inv), q3 = (int)rintf(v[i].w * inv);
        o[i] = (u32)(q0 & 255) | ((u32)(q1 & 255) << 8) |
               ((u32)(q2 & 255) << 16) | ((u32)(q3 & 255) << 24);
    }
    *(uint4*)(xq + (size_t)r * K + t * 16) = make_uint4(o[0], o[1], o[2], o[3]);
}

__device__ __forceinline__ u32 pk8(int4 a) {
    return (u32)(a.x & 255) | ((u32)(a.y & 255) << 8) |
           ((u32)(a.z & 255) << 16) | ((u32)(a.w & 255) << 24);
}

// int32 codes [-8,7] -> i8 (exact)
__global__ void quant_w_kernel(const int4* __restrict__ q, uint4* __restrict__ y, int n16) {
    int stride = gridDim.x * blockDim.x;
    for (int i = blockIdx.x * blockDim.x + threadIdx.x; i < n16; i += stride) {
        int4 a = q[4 * i], b = q[4 * i + 1], c = q[4 * i + 2], d = q[4 * i + 3];
        y[i] = make_uint4(pk8(a), pk8(b), pk8(c), pk8(d));
    }
}

// ===== 256x256 i8 GEMM with ONE-PHASE-AHEAD register pipeline (R8, verified pass) =====
// out[m][n] = acc[m][n] * sx[m] * scale[n] + bias[n]
// mfma_i32_16x16x64_i8, BKB=128 (8x16B slots/row), 3-bit slot swizzle (verified 0-conflict),
// 8 phases / 2 K-tiles. Phase p: {stage 1 pair; ds-read NEXT phase's frags (no RAW with
// this phase's MFMA); prio1; 16 MFMA on prev-phase regs; prio0; lgkmcnt(0) [cross-wave WAR:
// all reads done before any wave crosses barrier]; [vmcnt(2) gate]; barrier}.
// MFMA schedule: P1:X/KS0/MLO0 P2:X/KS1/MLO0 P3:X/KS0/MLO4 P4:X/KS1/MLO4, P5-P8 same on Y.
// Read-ahead: P8/P1/P4/P5 issue 8 reads (4 afr + 4 bfr), P2/P3/P6/P7 issue 4.
// Stage schedule + ledger (stage >= last-old-read+1 phase; gate-complete before 1st read):
//  P1:Y.A13  P2:Y.B23  P3:X'.A02 +GATE  P4:X'.B01  P5:X'.A13  P6:X'.B23  P7:Y'.A02 +GATE  P8:Y'.B01
//  (Y of iter i staged P7/P8 prev iter + P1/P2; drained by vmcnt(2)@P3, first read P4. X'
//  staged P3-P6; drained by vmcnt(2)@P7, first read P8. Gates keep 1 pair in flight.)

#define BM 256
#define BN 256
#define BKB 128   // K-bytes per tile (=128 i8)

template<int KSC, int MLOC, bool RDB, int BS, bool GATE, typename F>
__device__ __forceinline__ void phaseRA(
    const char* aN, const char* bN, int mloN,
    i32x4 (&afrC)[4], i32x4 (&afrN)[4],
    i32x4 (&bfr)[2][4], i32x4 (&acc)[8][4], F&& stage)
{
    stage();
    if (RDB) {
#pragma unroll
        for (int fn = 0; fn < 4; ++fn)
            bfr[BS][fn] = *(const i32x4*)(bN + fn * 2048);
    }
#pragma unroll
    for (int f = 0; f < 4; ++f)
        afrN[f] = *(const i32x4*)(aN + (mloN + f) * 2048);
    __builtin_amdgcn_s_setprio(1);
#pragma unroll
    for (int f = 0; f < 4; ++f)
#pragma unroll
        for (int fn = 0; fn < 4; ++fn)
            acc[MLOC + f][fn] = __builtin_amdgcn_mfma_i32_16x16x64_i8(
                bfr[KSC][fn], afrC[f], acc[MLOC + f][fn], 0, 0, 0);  // swapped: D col->m
    __builtin_amdgcn_s_setprio(0);
    asm volatile("s_waitcnt lgkmcnt(0)" ::: "memory");
    if (GATE) asm volatile("s_waitcnt vmcnt(2)" ::: "memory");
    __builtin_amdgcn_s_barrier();
}

__global__ __launch_bounds__(512, 2) void gemm256_i8(
    const u8* __restrict__ A,       // [M][K] i8 (x quantized per-row)
    const u8* __restrict__ W,       // [N][K] i8 (exact int4)
    const float* __restrict__ sx,   // [M] x row scales
    const float* __restrict__ scale,
    const float* __restrict__ bias,
    float* __restrict__ C,
    int M, int N, int K)
{
    __shared__ alignas(1024) char lds[131072];  // buf0(X): A@0 B@32768 ; buf1(Y): A@65536 B@98304

    const int nwg = gridDim.x;
    int bid = blockIdx.x;
    if ((nwg & 7) == 0) { int cpx = nwg >> 3; bid = (bid & 7) * cpx + (bid >> 3); }
    const int ntn = N / BN;
    const int tm = bid / ntn, tn = bid % ntn;

    const int t = threadIdx.x;
    const int l = t & 63;
    const int w = t >> 6;
    const int wm = w >> 2, wn = w & 3;       // 2 x 4 wave grid; wave tile 128x64
    const size_t Kz = (size_t)K;             // row stride in BYTES (i8)

    // ---- staging: linear LDS dest; pre-swizzled global source.
    const int sRow = t >> 3;                              // 0..63 within 64-row chunk
    const int sCol = (((t & 7) ^ ((t >> 3) & 7)) * 16);   // logical byte offset in row
    const u8* aSrc = A + (size_t)(tm * BM + sRow) * Kz + sCol;
    const u8* bSrc = W + (size_t)(tn * BN + sRow) * Kz + sCol;
    const int wByte = w * 1024;

    char* dA0 = lds + wByte;
    char* dB0 = lds + 32768 + wByte;
    char* dA1 = lds + 65536 + wByte;
    char* dB1 = lds + 98304 + wByte;

    // ---- reader bases: logical slot = (l>>4) | (KS<<2); physical = logical ^ (l&7).
    const int rowA = (wm * 128 + (l & 15)) * 128;
    const int rowB = (wn * 64  + (l & 15)) * 128;
    const int sl0 = (((l >> 4) | 0) ^ (l & 7)) * 16;   // KS=0: k 0..63
    const int sl1 = (((l >> 4) | 4) ^ (l & 7)) * 16;   // KS=1: k 64..127

    const char* aX0 = lds +         rowA + sl0;
    const char* aX1 = lds +         rowA + sl1;
    const char* bX0 = lds + 32768 + rowB + sl0;
    const char* bX1 = lds + 32768 + rowB + sl1;
    const char* aY0 = lds + 65536 + rowA + sl0;
    const char* aY1 = lds + 65536 + rowA + sl1;
    const char* bY0 = lds + 98304 + rowB + sl0;
    const char* bY1 = lds + 98304 + rowB + sl1;

    i32x4 acc[8][4];
#pragma unroll
    for (int i = 0; i < 8; ++i)
#pragma unroll
        for (int j = 0; j < 4; ++j) acc[i][j] = (i32x4){0, 0, 0, 0};

    const int NT = K / BKB;   // 32 K-tiles

    auto stagePair = [&](const u8* src, char* dst, int kt, int c0, int c1) {
        const u8* s0 = src + (size_t)c0 * 64 * Kz + (size_t)kt * BKB;
        const u8* s1 = src + (size_t)c1 * 64 * Kz + (size_t)kt * BKB;
        __builtin_amdgcn_global_load_lds((const AS1 void*)s0, (AS3 void*)(dst + c0 * 8192), 16, 0, 0);
        __builtin_amdgcn_global_load_lds((const AS1 void*)s1, (AS3 void*)(dst + c1 * 8192), 16, 0, 0);
    };

    // ---- prologue: X(tile0) full -> buf0; Y(tile1) A02+B01 -> buf1; counted gate;
    // then P0 reads (X KS0 MLO0 frags + bfr[0]) for P1's MFMA.
    stagePair(aSrc, dA0, 0, 0, 2);
    stagePair(bSrc, dB0, 0, 0, 1);
    stagePair(bSrc, dB0, 0, 2, 3);
    stagePair(aSrc, dA0, 0, 1, 3);
    stagePair(aSrc, dA1, 1, 0, 2);   // Y.A02
    stagePair(bSrc, dB1, 1, 0, 1);   // Y.B01
    asm volatile("s_waitcnt vmcnt(4)" ::: "memory");
    __builtin_amdgcn_s_barrier();

    i32x4 bfr[2][4];
    i32x4 afrA[4], afrB[4];
#pragma unroll
    for (int fn = 0; fn < 4; ++fn)
        bfr[0][fn] = *(const i32x4*)(bX0 + fn * 2048);
#pragma unroll
    for (int f = 0; f < 4; ++f)
        afrA[f] = *(const i32x4*)(aX0 + f * 2048);

#pragma unroll 1
    for (int i = 0; i < NT / 2; ++i) {
        const int yt = 2 * i + 1;
        const int e  = (2 * i + 2) & (NT - 1);   // wraps harmlessly on last iter
        const int o  = (2 * i + 3) & (NT - 1);
        // P1: MFMA X/KS0/MLO0(afrA); read aX1 MLO0 -> afrB, bX1 -> bfr[1]; stage Y.A13
        phaseRA<0, 0, true , 1, false>(aX1, bX1, 0, afrA, afrB, bfr, acc,
            [&] { stagePair(aSrc, dA1, yt, 1, 3); });
        // P2: MFMA X/KS1/MLO0(afrB); read aX0 MLO4 -> afrA; stage Y.B23
        phaseRA<1, 0, false, 0, false>(aX0, bX0, 4, afrB, afrA, bfr, acc,
            [&] { stagePair(bSrc, dB1, yt, 2, 3); });
        // P3: MFMA X/KS0/MLO4(afrA); read aX1 MLO4 -> afrB; stage X'.A02; GATE
        phaseRA<0, 4, false, 0, true >(aX1, bX1, 4, afrA, afrB, bfr, acc,
            [&] { stagePair(aSrc, dA0, e, 0, 2); });
        // P4: MFMA X/KS1/MLO4(afrB); read aY0 MLO0 -> afrA, bY0 -> bfr[0]; stage X'.B01
        phaseRA<1, 4, true , 0, false>(aY0, bY0, 0, afrB, afrA, bfr, acc,
            [&] { stagePair(bSrc, dB0, e, 0, 1); });
        // P5: MFMA Y/KS0/MLO0(afrA); read aY1 MLO0 -> afrB, bY1 -> bfr[1]; stage X'.A13
        phaseRA<0, 0, true , 1, false>(aY1, bY1, 0, afrA, afrB, bfr, acc,
            [&] { stagePair(aSrc, dA0, e, 1, 3); });
        // P6: MFMA Y/KS1/MLO0(afrB); read aY0 MLO4 -> afrA; stage X'.B23
        phaseRA<1, 0, false, 0, false>(aY0, bY0, 4, afrB, afrA, bfr, acc,
            [&] { stagePair(bSrc, dB0, e, 2, 3); });
        // P7: MFMA Y/KS0/MLO4(afrA); read aY1 MLO4 -> afrB; stage Y'.A02; GATE
        phaseRA<0, 4, false, 0, true >(aY1, bY1, 4, afrA, afrB, bfr, acc,
            [&] { stagePair(aSrc, dA1, o, 0, 2); });
        // P8: MFMA Y/KS1/MLO4(afrB); read aX0 MLO0 -> afrA, bX0 -> bfr[0]; stage Y'.B01
        phaseRA<1, 4, true , 0, false>(aX0, bX0, 0, afrB, afrA, bfr, acc,
            [&] { stagePair(bSrc, dB1, o, 0, 1); });
    }

    // ---- epilogue (swapped D): col(l&15)->m, row((l>>4)*4+r)->n
    const int mB = tm * BM + wm * 128 + (l & 15);
    const int nB = tn * BN + wn * 64 + 4 * (l >> 4);
    float sxv[8];
#pragma unroll
    for (int f = 0; f < 8; ++f) sxv[f] = sx[mB + f * 16];
#pragma unroll
    for (int fn = 0; fn < 4; ++fn) {
        const int n0 = nB + fn * 16;
        const float4 s4 = *(const float4*)(scale + n0);
        const float4 b4 = *(const float4*)(bias + n0);
#pragma unroll
        for (int f = 0; f < 8; ++f) {
            const int m = mB + f * 16;
            const float sm = sxv[f];
            float4 v;
            v.x = (float)acc[f][fn][0] * (sm * s4.x) + b4.x;
            v.y = (float)acc[f][fn][1] * (sm * s4.y) + b4.y;
            v.z = (float)acc[f][fn][2] * (sm * s4.z) + b4.z;
            v.w = (float)acc[f][fn][3] * (sm * s4.w) + b4.w;
            *(float4*)(C + (size_t)m * N + n0) = v;
        }
    }
}

extern "C" void kernel_launch(void* const* d_in, const int* in_sizes, int n_in,
                              void* d_out, int out_size, void* d_ws, size_t ws_size,
                              hipStream_t stream) {
    const float* x     = (const float*)d_in[0];
    const int*   qw    = (const int*)d_in[1];
    const float* scale = (const float*)d_in[2];
    const float* bias  = (const float*)d_in[3];
    float*       out   = (float*)d_out;

    const int N = in_sizes[2];            // DOUT = 4096
    const int K = in_sizes[1] / N;        // DIN  = 4096
    const int M = in_sizes[0] / K;        // B*S  = 8192

    // workspace: xq [M*K] i8, wq [N*K] i8, sx [M] f32  (~50.4 MB)
    u8*    xq = (u8*)d_ws;
    u8*    wq = xq + (size_t)M * K;
    float* sx = (float*)(wq + (size_t)N * K);

    quant_x_kernel<<<M, 256, 0, stream>>>(x, xq, sx, K);
    quant_w_kernel<<<2048, 256, 0, stream>>>((const int4*)qw, (uint4*)wq, (N * K) / 16);

    const int grid = (M / BM) * (N / BN); // 512
    gemm256_i8<<<grid, 512, 0, stream>>>(xq, wq, sx, scale, bias, out, M, N, K);
}